// Round 2
// baseline (1152.333 us; speedup 1.0000x reference)
//
#include <hip/hip_runtime.h>

#define N_NODES 50000
#define N_EDGES 800000
#define DIM 128
#define OUTD 47

// ---------------- CSR build ----------------
__global__ void k_count(const int* __restrict__ dst, int* __restrict__ deg) {
    int e = blockIdx.x * 256 + threadIdx.x;
    if (e < N_EDGES) atomicAdd(&deg[dst[e]], 1);
}

__global__ __launch_bounds__(1024) void k_scan(const int* __restrict__ deg,
                                               int* __restrict__ row_ptr,
                                               int* __restrict__ fill) {
    __shared__ int sums[1024];
    const int tid = threadIdx.x;
    const int CH = (N_NODES + 1023) / 1024; // 49
    int lo = tid * CH; if (lo > N_NODES) lo = N_NODES;
    int hi = lo + CH;  if (hi > N_NODES) hi = N_NODES;
    int s = 0;
    for (int i = lo; i < hi; ++i) s += deg[i];
    sums[tid] = s;
    __syncthreads();
    for (int off = 1; off < 1024; off <<= 1) { // read -> barrier -> write -> barrier (race-free)
        int t = (tid >= off) ? sums[tid - off] : 0;
        __syncthreads();
        sums[tid] += t;
        __syncthreads();
    }
    int run = sums[tid] - s; // exclusive prefix for this chunk
    for (int i = lo; i < hi; ++i) {
        row_ptr[i] = run; fill[i] = run; run += deg[i];
    }
    if (tid == 1023) row_ptr[N_NODES] = run; // == N_EDGES
}

__global__ void k_fill(const int* __restrict__ src, const int* __restrict__ dst,
                       int* __restrict__ fill, int* __restrict__ src_sorted) {
    int e = blockIdx.x * 256 + threadIdx.x;
    if (e < N_EDGES) {
        int p = atomicAdd(&fill[dst[e]], 1);
        src_sorted[p] = src[e];
    }
}

// ---------------- mean aggregation (gather-side, no float atomics) ----------------
__global__ __launch_bounds__(128) void k_agg(const float* __restrict__ h,
                                             const int* __restrict__ row_ptr,
                                             const int* __restrict__ src_sorted,
                                             float* __restrict__ mean) {
    const int n = blockIdx.x;
    const int f = threadIdx.x;
    const int start = row_ptr[n], end = row_ptr[n + 1];
    float acc = 0.f;
    int e = start;
    for (; e + 4 <= end; e += 4) {
        int s0 = src_sorted[e], s1 = src_sorted[e + 1];
        int s2 = src_sorted[e + 2], s3 = src_sorted[e + 3];
        float v0 = h[(size_t)s0 * DIM + f];
        float v1 = h[(size_t)s1 * DIM + f];
        float v2 = h[(size_t)s2 * DIM + f];
        float v3 = h[(size_t)s3 * DIM + f];
        acc = acc + ((v0 + v1) + (v2 + v3));
    }
    for (; e < end; ++e) acc += h[(size_t)src_sorted[e] * DIM + f];
    int d = end - start;
    mean[(size_t)n * DIM + f] = (d > 0) ? acc / (float)d : 0.0f;
}

// ---------------- fused GEMM: out = h@Wself^T + b + mean@Wneigh^T (+relu) ----------------
// fp32 weights staged in LDS, layout [k/4][j][4] floats: lane j's ds_read_b128 at
// offset (c*JT+j)*16B -> 64 lanes read 1KB contiguous -> conflict-free.
// One wave per node (lanes = JT output features), 4 nodes per 256-thread block.
template <int JT, bool RELU>
__global__ __launch_bounds__(256) void k_gemm(const float* __restrict__ h,
                                              const float* __restrict__ mean,
                                              const float* __restrict__ wself,
                                              const float* __restrict__ wneigh,
                                              const float* __restrict__ bias,
                                              float* __restrict__ out, int outdim) {
    __shared__ __align__(16) float wlds[64 * JT * 4]; // 64 k4-chunks (self 32 | neigh 32)
    const int tid = threadIdx.x;
    const int j0 = blockIdx.y * JT;
    for (int idx = tid; idx < JT * 64; idx += 256) {
        int j = idx >> 6;      // row within tile
        int q = idx & 63;      // k4 index in concat [self(32) | neigh(32)]
        const float* sw = (q < 32) ? (wself  + (size_t)(j0 + j) * DIM + q * 4)
                                   : (wneigh + (size_t)(j0 + j) * DIM + (q - 32) * 4);
        float4 v = *(const float4*)sw;
        *(float4*)&wlds[((size_t)q * JT + j) * 4] = v;
    }
    __syncthreads();
    const int local = tid >> 6;    // wave index = node within block (wave-uniform)
    const int j = tid & 63;
    const int jc = (j < JT) ? j : 0;
    int n = blockIdx.x * 4 + local;
    n = __builtin_amdgcn_readfirstlane(n); // force scalar row pointers
    const float4* __restrict__ hrow = (const float4*)(h + (size_t)n * DIM);
    const float4* __restrict__ mrow = (const float4*)(mean + (size_t)n * DIM);
    float a0 = 0.f, a1 = 0.f, a2 = 0.f, a3 = 0.f;
    #pragma unroll
    for (int c = 0; c < 32; ++c) { // self half
        float4 hv = hrow[c];
        float4 w = *(const float4*)&wlds[((size_t)c * JT + jc) * 4];
        a0 = fmaf(hv.x, w.x, a0);
        a1 = fmaf(hv.y, w.y, a1);
        a2 = fmaf(hv.z, w.z, a2);
        a3 = fmaf(hv.w, w.w, a3);
    }
    #pragma unroll
    for (int c = 0; c < 32; ++c) { // neigh half
        float4 hv = mrow[c];
        float4 w = *(const float4*)&wlds[((size_t)(32 + c) * JT + jc) * 4];
        a0 = fmaf(hv.x, w.x, a0);
        a1 = fmaf(hv.y, w.y, a1);
        a2 = fmaf(hv.z, w.z, a2);
        a3 = fmaf(hv.w, w.w, a3);
    }
    if (j < JT) {
        float acc = (a0 + a1) + (a2 + a3) + bias[j0 + j];
        if (RELU) acc = fmaxf(acc, 0.f);
        out[(size_t)n * outdim + (j0 + j)] = acc;
    }
}

extern "C" void kernel_launch(void* const* d_in, const int* in_sizes, int n_in,
                              void* d_out, int out_size, void* d_ws, size_t ws_size,
                              hipStream_t stream) {
    const float* x   = (const float*)d_in[0];
    const int*   src = (const int*)d_in[1];
    const int*   dst = (const int*)d_in[2];
    const float* ws1 = (const float*)d_in[3];
    const float* wn1 = (const float*)d_in[4];
    const float* b1  = (const float*)d_in[5];
    const float* ws2 = (const float*)d_in[6];
    const float* wn2 = (const float*)d_in[7];
    const float* b2  = (const float*)d_in[8];
    const float* ws3 = (const float*)d_in[9];
    const float* wn3 = (const float*)d_in[10];
    const float* b3  = (const float*)d_in[11];

    char* p = (char*)d_ws;
    auto alloc = [&](size_t bytes) { char* r = p; p += (bytes + 255) & ~(size_t)255; return r; };
    int*   deg     = (int*)alloc((size_t)N_NODES * 4);
    int*   row_ptr = (int*)alloc((size_t)(N_NODES + 1) * 4);
    int*   fill    = (int*)alloc((size_t)N_NODES * 4);
    int*   srcs    = (int*)alloc((size_t)N_EDGES * 4);
    float* mean    = (float*)alloc((size_t)N_NODES * DIM * 4);
    float* h1      = (float*)alloc((size_t)N_NODES * DIM * 4);
    float* h2      = (float*)alloc((size_t)N_NODES * DIM * 4);

    // CSR build (ws re-poisoned every call -> rebuild every call)
    hipMemsetAsync(deg, 0, (size_t)N_NODES * 4, stream);
    k_count<<<(N_EDGES + 255) / 256, 256, 0, stream>>>(dst, deg);
    k_scan<<<1, 1024, 0, stream>>>(deg, row_ptr, fill);
    k_fill<<<(N_EDGES + 255) / 256, 256, 0, stream>>>(src, dst, fill, srcs);

    // layer 1: x -> h1
    k_agg<<<N_NODES, 128, 0, stream>>>(x, row_ptr, srcs, mean);
    {
        dim3 g(N_NODES / 4, DIM / 32);
        k_gemm<32, true><<<g, 256, 0, stream>>>(x, mean, ws1, wn1, b1, h1, DIM);
    }
    // layer 2: h1 -> h2
    k_agg<<<N_NODES, 128, 0, stream>>>(h1, row_ptr, srcs, mean);
    {
        dim3 g(N_NODES / 4, DIM / 32);
        k_gemm<32, true><<<g, 256, 0, stream>>>(h1, mean, ws2, wn2, b2, h2, DIM);
    }
    // layer 3: h2 -> out (47 features, single tile)
    k_agg<<<N_NODES, 128, 0, stream>>>(h2, row_ptr, srcs, mean);
    {
        dim3 g(N_NODES / 4, 1);
        k_gemm<OUTD, false><<<g, 256, 0, stream>>>(h2, mean, ws3, wn3, b3, (float*)d_out, OUTD);
    }
}

// Round 3
// 753.837 us; speedup vs baseline: 1.5286x; 1.5286x over previous
//
#include <hip/hip_runtime.h>

#define N_NODES 50000
#define N_EDGES 800000
#define DIM 128
#define OUTD 47

// ---------------- CSR build ----------------
__global__ void k_count(const int* __restrict__ dst, int* __restrict__ deg) {
    int e = blockIdx.x * 256 + threadIdx.x;
    if (e < N_EDGES) atomicAdd(&deg[dst[e]], 1);
}

__global__ __launch_bounds__(1024) void k_scan(const int* __restrict__ deg,
                                               int* __restrict__ row_ptr,
                                               int* __restrict__ fill) {
    __shared__ int sums[1024];
    const int tid = threadIdx.x;
    const int CH = (N_NODES + 1023) / 1024; // 49
    int lo = tid * CH; if (lo > N_NODES) lo = N_NODES;
    int hi = lo + CH;  if (hi > N_NODES) hi = N_NODES;
    int s = 0;
    for (int i = lo; i < hi; ++i) s += deg[i];
    sums[tid] = s;
    __syncthreads();
    for (int off = 1; off < 1024; off <<= 1) {
        int t = (tid >= off) ? sums[tid - off] : 0;
        __syncthreads();
        sums[tid] += t;
        __syncthreads();
    }
    int run = sums[tid] - s;
    for (int i = lo; i < hi; ++i) {
        row_ptr[i] = run; fill[i] = run; run += deg[i];
    }
    if (tid == 1023) row_ptr[N_NODES] = run;
}

__global__ void k_fill(const int* __restrict__ src, const int* __restrict__ dst,
                       int* __restrict__ fill, int* __restrict__ src_sorted) {
    int e = blockIdx.x * 256 + threadIdx.x;
    if (e < N_EDGES) {
        int p = atomicAdd(&fill[dst[e]], 1);
        src_sorted[p] = src[e];
    }
}

// ---------------- mean aggregation: one wave per node, float2 lanes ----------------
__global__ __launch_bounds__(256) void k_agg(const float* __restrict__ h,
                                             const int* __restrict__ row_ptr,
                                             const int* __restrict__ srcs,
                                             float* __restrict__ mean) {
    const int w = threadIdx.x >> 6;
    const int l = threadIdx.x & 63;
    const int n = blockIdx.x * 4 + w;
    const int start = row_ptr[n], end = row_ptr[n + 1]; // wave-uniform
    const float2* __restrict__ hp = (const float2*)h;
    float ax = 0.f, ay = 0.f;
    int e = start;
    for (; e + 2 <= end; e += 2) {
        int s0 = __builtin_amdgcn_readfirstlane(srcs[e]);
        int s1 = __builtin_amdgcn_readfirstlane(srcs[e + 1]);
        float2 v0 = hp[(size_t)s0 * 64 + l];
        float2 v1 = hp[(size_t)s1 * 64 + l];
        ax += v0.x + v1.x; ay += v0.y + v1.y;
    }
    if (e < end) {
        int s0 = __builtin_amdgcn_readfirstlane(srcs[e]);
        float2 v0 = hp[(size_t)s0 * 64 + l];
        ax += v0.x; ay += v0.y;
    }
    int d = end - start;
    float inv = (d > 0) ? 1.f / (float)d : 0.f;
    float2 r; r.x = ax * inv; r.y = ay * inv;
    ((float2*)mean)[(size_t)n * 64 + l] = r;
}

// ---------------- register-blocked fused GEMM ----------------
// C[n][j] = sum_k cat(A,MEAN)[n][k] * cat(wself,wneigh)[j][k] + b[j] (+relu)
// Block: 128 nodes x NT feats, 128 threads (tx 0..7 feats-octet, ty 0..15 node-octet),
// each thread 8 nodes x 8 feats. K chunked by 32, both operands staged in LDS.
// LDS row stride 36 floats (16B aligned; bank pattern per-inst clustered but
// spread across instructions -> pipelined; verify with SQ_LDS_BANK_CONFLICT).
template <int NT, bool RELU, bool GUARDJ>
__global__ __launch_bounds__(128) void k_gemm(const float* __restrict__ A,
                                              const float* __restrict__ MEAN,
                                              const float* __restrict__ wself,
                                              const float* __restrict__ wneigh,
                                              const float* __restrict__ bias,
                                              float* __restrict__ out, int outdim) {
    __shared__ __align__(16) float hlds[128 * 36];
    __shared__ __align__(16) float wlds[NT * 36];
    constexpr int WR = NT / 16; // w-staging float4s per thread
    const int tid = threadIdx.x;
    const int tx = tid & 7, ty = tid >> 3;
    const int m0 = blockIdx.x * 128;
    const int j0 = blockIdx.y * NT;
    float acc[8][8] = {};
    #pragma unroll 1
    for (int c = 0; c < 8; ++c) {
        const float* __restrict__ Asrc = (c < 4) ? A : MEAN;
        const float* __restrict__ Wsrc = (c < 4) ? wself : wneigh;
        const int koff = (c & 3) * 32;
        float4 hreg[8];
        #pragma unroll
        for (int r = 0; r < 8; ++r) {
            int t = tid + 128 * r;     // t = m*8 + kq
            int m = t >> 3, kq = t & 7;
            int node = m0 + m; if (node >= N_NODES) node = N_NODES - 1;
            hreg[r] = *(const float4*)(Asrc + (size_t)node * DIM + koff + kq * 4);
        }
        float4 wreg[WR];
        #pragma unroll
        for (int r = 0; r < WR; ++r) {
            int t = tid + 128 * r;     // t = n*8 + kq
            int n = t >> 3, kq = t & 7;
            int row = j0 + n;
            if (GUARDJ && row >= outdim) row = outdim - 1;
            wreg[r] = *(const float4*)(Wsrc + (size_t)row * DIM + koff + kq * 4);
        }
        __syncthreads(); // previous chunk's compute done before overwrite
        #pragma unroll
        for (int r = 0; r < 8; ++r) {
            int t = tid + 128 * r; int m = t >> 3, kq = t & 7;
            *(float4*)&hlds[m * 36 + kq * 4] = hreg[r];
        }
        #pragma unroll
        for (int r = 0; r < WR; ++r) {
            int t = tid + 128 * r; int n = t >> 3, kq = t & 7;
            *(float4*)&wlds[n * 36 + kq * 4] = wreg[r];
        }
        __syncthreads();
        #pragma unroll
        for (int kk = 0; kk < 32; kk += 4) {
            float4 a[8], b[8];
            #pragma unroll
            for (int i = 0; i < 8; ++i) a[i] = *(const float4*)&hlds[(ty * 8 + i) * 36 + kk];
            #pragma unroll
            for (int i = 0; i < 8; ++i) b[i] = *(const float4*)&wlds[(tx * 8 + i) * 36 + kk];
            #pragma unroll
            for (int i = 0; i < 8; ++i)
                #pragma unroll
                for (int j = 0; j < 8; ++j)
                    acc[i][j] = fmaf(a[i].w, b[j].w,
                                fmaf(a[i].z, b[j].z,
                                fmaf(a[i].y, b[j].y,
                                fmaf(a[i].x, b[j].x, acc[i][j]))));
        }
    }
    // epilogue
    if (!GUARDJ) {
        float4 bv0 = *(const float4*)(bias + j0 + tx * 8);
        float4 bv1 = *(const float4*)(bias + j0 + tx * 8 + 4);
        #pragma unroll
        for (int i = 0; i < 8; ++i) {
            int node = m0 + ty * 8 + i;
            if (node >= N_NODES) break;
            float4 o0, o1;
            o0.x = acc[i][0] + bv0.x; o0.y = acc[i][1] + bv0.y;
            o0.z = acc[i][2] + bv0.z; o0.w = acc[i][3] + bv0.w;
            o1.x = acc[i][4] + bv1.x; o1.y = acc[i][5] + bv1.y;
            o1.z = acc[i][6] + bv1.z; o1.w = acc[i][7] + bv1.w;
            if (RELU) {
                o0.x = fmaxf(o0.x, 0.f); o0.y = fmaxf(o0.y, 0.f);
                o0.z = fmaxf(o0.z, 0.f); o0.w = fmaxf(o0.w, 0.f);
                o1.x = fmaxf(o1.x, 0.f); o1.y = fmaxf(o1.y, 0.f);
                o1.z = fmaxf(o1.z, 0.f); o1.w = fmaxf(o1.w, 0.f);
            }
            float* op = out + (size_t)node * outdim + j0 + tx * 8;
            *(float4*)op = o0;
            *(float4*)(op + 4) = o1;
        }
    } else {
        #pragma unroll
        for (int i = 0; i < 8; ++i) {
            int node = m0 + ty * 8 + i;
            if (node >= N_NODES) break;
            #pragma unroll
            for (int j = 0; j < 8; ++j) {
                int col = j0 + tx * 8 + j;
                if (col >= outdim) break;
                float v = acc[i][j] + bias[col];
                if (RELU) v = fmaxf(v, 0.f);
                out[(size_t)node * outdim + col] = v;
            }
        }
    }
}

extern "C" void kernel_launch(void* const* d_in, const int* in_sizes, int n_in,
                              void* d_out, int out_size, void* d_ws, size_t ws_size,
                              hipStream_t stream) {
    const float* x   = (const float*)d_in[0];
    const int*   src = (const int*)d_in[1];
    const int*   dst = (const int*)d_in[2];
    const float* ws1 = (const float*)d_in[3];
    const float* wn1 = (const float*)d_in[4];
    const float* b1  = (const float*)d_in[5];
    const float* ws2 = (const float*)d_in[6];
    const float* wn2 = (const float*)d_in[7];
    const float* b2  = (const float*)d_in[8];
    const float* ws3 = (const float*)d_in[9];
    const float* wn3 = (const float*)d_in[10];
    const float* b3  = (const float*)d_in[11];

    char* p = (char*)d_ws;
    auto alloc = [&](size_t bytes) { char* r = p; p += (bytes + 255) & ~(size_t)255; return r; };
    int*   deg     = (int*)alloc((size_t)N_NODES * 4);
    int*   row_ptr = (int*)alloc((size_t)(N_NODES + 1) * 4);
    int*   fill    = (int*)alloc((size_t)N_NODES * 4);
    int*   srcs    = (int*)alloc((size_t)N_EDGES * 4);
    float* mean    = (float*)alloc((size_t)N_NODES * DIM * 4);
    float* h1      = (float*)alloc((size_t)N_NODES * DIM * 4);
    float* h2      = (float*)alloc((size_t)N_NODES * DIM * 4);

    hipMemsetAsync(deg, 0, (size_t)N_NODES * 4, stream);
    k_count<<<(N_EDGES + 255) / 256, 256, 0, stream>>>(dst, deg);
    k_scan<<<1, 1024, 0, stream>>>(deg, row_ptr, fill);
    k_fill<<<(N_EDGES + 255) / 256, 256, 0, stream>>>(src, dst, fill, srcs);

    const int MB = (N_NODES + 127) / 128; // 391 node tiles

    // layer 1
    k_agg<<<N_NODES / 4, 256, 0, stream>>>(x, row_ptr, srcs, mean);
    k_gemm<64, true, false><<<dim3(MB, 2), 128, 0, stream>>>(x, mean, ws1, wn1, b1, h1, DIM);
    // layer 2
    k_agg<<<N_NODES / 4, 256, 0, stream>>>(h1, row_ptr, srcs, mean);
    k_gemm<64, true, false><<<dim3(MB, 2), 128, 0, stream>>>(h1, mean, ws2, wn2, b2, h2, DIM);
    // layer 3
    k_agg<<<N_NODES / 4, 256, 0, stream>>>(h2, row_ptr, srcs, mean);
    k_gemm<64, false, true><<<dim3(MB, 1), 128, 0, stream>>>(h2, mean, ws3, wn3, b3, (float*)d_out, OUTD);
}

// Round 4
// 560.386 us; speedup vs baseline: 2.0563x; 1.3452x over previous
//
#include <hip/hip_runtime.h>

#define N_NODES 50000
#define N_EDGES 800000
#define DIM 128
#define OUTD 47

typedef __attribute__((ext_vector_type(8))) short v8s;
typedef __attribute__((ext_vector_type(4))) float v4f;

static __device__ __forceinline__ unsigned short f2bf(float f) {
    union { float f; unsigned int u; } v; v.f = f;
    unsigned int x = v.u;
    return (unsigned short)((x + 0x7fffu + ((x >> 16) & 1u)) >> 16); // RNE
}

// ---------------- CSR build ----------------
__global__ void k_count(const int* __restrict__ dst, int* __restrict__ deg) {
    int e = blockIdx.x * 256 + threadIdx.x;
    if (e < N_EDGES) atomicAdd(&deg[dst[e]], 1);
}

__global__ __launch_bounds__(1024) void k_scan(const int* __restrict__ deg,
                                               int* __restrict__ row_ptr,
                                               int* __restrict__ fill) {
    __shared__ int sums[1024];
    const int tid = threadIdx.x;
    const int CH = (N_NODES + 1023) / 1024; // 49
    int lo = tid * CH; if (lo > N_NODES) lo = N_NODES;
    int hi = lo + CH;  if (hi > N_NODES) hi = N_NODES;
    int s = 0;
    for (int i = lo; i < hi; ++i) s += deg[i];
    sums[tid] = s;
    __syncthreads();
    for (int off = 1; off < 1024; off <<= 1) {
        int t = (tid >= off) ? sums[tid - off] : 0;
        __syncthreads();
        sums[tid] += t;
        __syncthreads();
    }
    int run = sums[tid] - s;
    for (int i = lo; i < hi; ++i) {
        row_ptr[i] = run; fill[i] = run; run += deg[i];
    }
    if (tid == 1023) row_ptr[N_NODES] = run;
}

__global__ void k_fill(const int* __restrict__ src, const int* __restrict__ dst,
                       int* __restrict__ fill, int* __restrict__ src_sorted) {
    int e = blockIdx.x * 256 + threadIdx.x;
    if (e < N_EDGES) {
        int p = atomicAdd(&fill[dst[e]], 1);
        src_sorted[p] = src[e];
    }
}

// ---------------- mean aggregation: one wave per node, float2 lanes ----------------
__global__ __launch_bounds__(256) void k_agg(const float* __restrict__ h,
                                             const int* __restrict__ row_ptr,
                                             const int* __restrict__ srcs,
                                             float* __restrict__ mean) {
    const int w = threadIdx.x >> 6;
    const int l = threadIdx.x & 63;
    const int n = blockIdx.x * 4 + w;
    const int start = row_ptr[n], end = row_ptr[n + 1]; // wave-uniform
    const float2* __restrict__ hp = (const float2*)h;
    float ax = 0.f, ay = 0.f;
    int e = start;
    for (; e + 4 <= end; e += 4) {
        int s0 = __builtin_amdgcn_readfirstlane(srcs[e]);
        int s1 = __builtin_amdgcn_readfirstlane(srcs[e + 1]);
        int s2 = __builtin_amdgcn_readfirstlane(srcs[e + 2]);
        int s3 = __builtin_amdgcn_readfirstlane(srcs[e + 3]);
        float2 v0 = hp[(size_t)s0 * 64 + l];
        float2 v1 = hp[(size_t)s1 * 64 + l];
        float2 v2 = hp[(size_t)s2 * 64 + l];
        float2 v3 = hp[(size_t)s3 * 64 + l];
        ax += (v0.x + v1.x) + (v2.x + v3.x);
        ay += (v0.y + v1.y) + (v2.y + v3.y);
    }
    for (; e < end; ++e) {
        int s0 = __builtin_amdgcn_readfirstlane(srcs[e]);
        float2 v0 = hp[(size_t)s0 * 64 + l];
        ax += v0.x; ay += v0.y;
    }
    int d = end - start;
    float inv = (d > 0) ? 1.f / (float)d : 0.f;
    float2 r; r.x = ax * inv; r.y = ay * inv;
    ((float2*)mean)[(size_t)n * 64 + l] = r;
}

// ---------------- weight convert: Wcat[j][0..127]=wself[j], [128..255]=wneigh[j], bf16 ----------------
__global__ void k_wcvt(const float* __restrict__ wself, const float* __restrict__ wneigh,
                       unsigned short* __restrict__ out, int J /*valid rows*/) {
    int idx = blockIdx.x * 256 + threadIdx.x; // one elem per thread, grid = Jpad
    int j = idx >> 8, k = idx & 255;
    float v = 0.f;
    if (j < J) v = (k < DIM) ? wself[j * DIM + k] : wneigh[j * DIM + (k - DIM)];
    out[idx] = f2bf(v);
}

// ---------------- MFMA GEMM: out[n][j] = cat(A,MEAN)[n][:] . Wcat[j][:] + b[j] (+relu) ----------------
// One wave per 16-node strip, NTILES 16x16 output tiles (all j), K=256 in 8 steps of 32.
// A fragment: lane(m + 16*quad) holds A[m][k0 + quad*8 + j], loaded from global fp32,
// converted to bf16 in-register. W fragment: lane(n + 16*quad) holds Wcat[n][k0+quad*8+j]
// (bf16, 16B/lane). D: col = lane&15, row = quad*4 + reg  [m89/m92-verified layouts].
// No LDS, no barriers -> no spill, high occupancy.
template <int NTILES, bool RELU>
__global__ __launch_bounds__(256) void k_gemm_mfma(const float* __restrict__ A,
                                                   const float* __restrict__ MEAN,
                                                   const unsigned short* __restrict__ Wb,
                                                   const float* __restrict__ bias,
                                                   float* __restrict__ out, int outdim) {
    const int lane = threadIdx.x & 63;
    const int wv = threadIdx.x >> 6;
    const int m0 = (blockIdx.x * 4 + wv) * 16;
    const int m = lane & 15, qd = lane >> 4;
    int node = m0 + m; if (node >= N_NODES) node = N_NODES - 1; // clamp loads
    const float* __restrict__ arow = A + (size_t)node * DIM;
    const float* __restrict__ mrow = MEAN + (size_t)node * DIM;

    v4f acc[NTILES] = {};
    #pragma unroll
    for (int c = 0; c < 8; ++c) {
        const float* __restrict__ srow = (c < 4) ? arow : mrow;
        const int ko = (c & 3) * 32 + qd * 8;
        float4 p = *(const float4*)(srow + ko);
        float4 q = *(const float4*)(srow + ko + 4);
        v8s af;
        af[0] = (short)f2bf(p.x); af[1] = (short)f2bf(p.y);
        af[2] = (short)f2bf(p.z); af[3] = (short)f2bf(p.w);
        af[4] = (short)f2bf(q.x); af[5] = (short)f2bf(q.y);
        af[6] = (short)f2bf(q.z); af[7] = (short)f2bf(q.w);
        const int kglob = c * 32 + qd * 8;
        #pragma unroll
        for (int t = 0; t < NTILES; ++t) {
            v8s wf = *(const v8s*)(Wb + (size_t)(t * 16 + m) * 256 + kglob);
            acc[t] = __builtin_amdgcn_mfma_f32_16x16x32_bf16(af, wf, acc[t], 0, 0, 0);
        }
    }
    // epilogue: D col = lane&15 (feature), row = qd*4 + r (node)
    #pragma unroll
    for (int t = 0; t < NTILES; ++t) {
        int col = t * 16 + m;
        bool colok = (col < outdim);
        float bv = colok ? bias[col] : 0.f;
        #pragma unroll
        for (int r = 0; r < 4; ++r) {
            int nrow = m0 + qd * 4 + r;
            if (colok && nrow < N_NODES) {
                float v = acc[t][r] + bv;
                if (RELU) v = fmaxf(v, 0.f);
                out[(size_t)nrow * outdim + col] = v;
            }
        }
    }
}

extern "C" void kernel_launch(void* const* d_in, const int* in_sizes, int n_in,
                              void* d_out, int out_size, void* d_ws, size_t ws_size,
                              hipStream_t stream) {
    const float* x   = (const float*)d_in[0];
    const int*   src = (const int*)d_in[1];
    const int*   dst = (const int*)d_in[2];
    const float* ws1 = (const float*)d_in[3];
    const float* wn1 = (const float*)d_in[4];
    const float* b1  = (const float*)d_in[5];
    const float* ws2 = (const float*)d_in[6];
    const float* wn2 = (const float*)d_in[7];
    const float* b2  = (const float*)d_in[8];
    const float* ws3 = (const float*)d_in[9];
    const float* wn3 = (const float*)d_in[10];
    const float* b3  = (const float*)d_in[11];

    char* p = (char*)d_ws;
    auto alloc = [&](size_t bytes) { char* r = p; p += (bytes + 255) & ~(size_t)255; return r; };
    int*   deg     = (int*)alloc((size_t)N_NODES * 4);
    int*   row_ptr = (int*)alloc((size_t)(N_NODES + 1) * 4);
    int*   fill    = (int*)alloc((size_t)N_NODES * 4);
    int*   srcs    = (int*)alloc((size_t)N_EDGES * 4);
    float* mean    = (float*)alloc((size_t)N_NODES * DIM * 4);
    float* h1      = (float*)alloc((size_t)N_NODES * DIM * 4);
    float* h2      = (float*)alloc((size_t)N_NODES * DIM * 4);
    unsigned short* wb1 = (unsigned short*)alloc((size_t)DIM * 256 * 2);
    unsigned short* wb2 = (unsigned short*)alloc((size_t)DIM * 256 * 2);
    unsigned short* wb3 = (unsigned short*)alloc((size_t)48 * 256 * 2);

    // weight conversion (tiny)
    k_wcvt<<<DIM, 256, 0, stream>>>(ws1, wn1, wb1, DIM);
    k_wcvt<<<DIM, 256, 0, stream>>>(ws2, wn2, wb2, DIM);
    k_wcvt<<<48,  256, 0, stream>>>(ws3, wn3, wb3, OUTD);

    // CSR build (ws re-poisoned every call -> rebuild every call)
    hipMemsetAsync(deg, 0, (size_t)N_NODES * 4, stream);
    k_count<<<(N_EDGES + 255) / 256, 256, 0, stream>>>(dst, deg);
    k_scan<<<1, 1024, 0, stream>>>(deg, row_ptr, fill);
    k_fill<<<(N_EDGES + 255) / 256, 256, 0, stream>>>(src, dst, fill, srcs);

    const int GB = (N_NODES + 63) / 64; // 782 blocks, 4 waves x 16 nodes each

    // layer 1
    k_agg<<<N_NODES / 4, 256, 0, stream>>>(x, row_ptr, srcs, mean);
    k_gemm_mfma<8, true><<<GB, 256, 0, stream>>>(x, mean, wb1, b1, h1, DIM);
    // layer 2
    k_agg<<<N_NODES / 4, 256, 0, stream>>>(h1, row_ptr, srcs, mean);
    k_gemm_mfma<8, true><<<GB, 256, 0, stream>>>(h1, mean, wb2, b2, h2, DIM);
    // layer 3
    k_agg<<<N_NODES / 4, 256, 0, stream>>>(h2, row_ptr, srcs, mean);
    k_gemm_mfma<3, false><<<GB, 256, 0, stream>>>(h2, mean, wb3, b3, (float*)d_out, OUTD);
}

// Round 5
// 400.013 us; speedup vs baseline: 2.8807x; 1.4009x over previous
//
#include <hip/hip_runtime.h>

#define N_NODES 50000
#define N_EDGES 800000
#define DIM 128
#define OUTD 47
#define NB_SCAN ((N_NODES + 255) / 256) // 196

typedef __attribute__((ext_vector_type(8))) short v8s;
typedef __attribute__((ext_vector_type(4))) float v4f;

static __device__ __forceinline__ unsigned short f2bf(float f) {
    union { float f; unsigned int u; } v; v.f = f;
    unsigned int x = v.u;
    return (unsigned short)((x + 0x7fffu + ((x >> 16) & 1u)) >> 16); // RNE
}
static __device__ __forceinline__ float lo_bf(unsigned int u) {
    union { unsigned int i; float f; } v; v.i = u << 16; return v.f;
}
static __device__ __forceinline__ float hi_bf(unsigned int u) {
    union { unsigned int i; float f; } v; v.i = u & 0xffff0000u; return v.f;
}

// ---------------- CSR build ----------------
__global__ void k_count(const int* __restrict__ dst, int* __restrict__ deg) {
    int e = blockIdx.x * 256 + threadIdx.x;
    if (e < N_EDGES) atomicAdd(&deg[dst[e]], 1);
}

// block sums of deg (256 elems per block)
__global__ __launch_bounds__(256) void k_bsum(const int* __restrict__ deg,
                                              int* __restrict__ bsum) {
    __shared__ int s[256];
    int i = blockIdx.x * 256 + threadIdx.x;
    int v = (i < N_NODES) ? deg[i] : 0;
    s[threadIdx.x] = v;
    __syncthreads();
    for (int off = 128; off > 0; off >>= 1) {
        if (threadIdx.x < off) s[threadIdx.x] += s[threadIdx.x + off];
        __syncthreads();
    }
    if (threadIdx.x == 0) bsum[blockIdx.x] = s[0];
}

// single-block scan of NB_SCAN block sums -> exclusive block offsets
__global__ __launch_bounds__(256) void k_scanb(const int* __restrict__ bsum,
                                               int* __restrict__ boff,
                                               int* __restrict__ row_ptr) {
    __shared__ int s[256];
    int t = threadIdx.x;
    int v = (t < NB_SCAN) ? bsum[t] : 0;
    s[t] = v;
    __syncthreads();
    for (int off = 1; off < 256; off <<= 1) {
        int u = (t >= off) ? s[t - off] : 0;
        __syncthreads();
        s[t] += u;
        __syncthreads();
    }
    if (t < NB_SCAN) boff[t] = s[t] - v; // exclusive
    if (t == 255) row_ptr[N_NODES] = s[255]; // total == N_EDGES
}

// per-block exclusive scan + global offset -> row_ptr, fill
__global__ __launch_bounds__(256) void k_scatter(const int* __restrict__ deg,
                                                 const int* __restrict__ boff,
                                                 int* __restrict__ row_ptr,
                                                 int* __restrict__ fill) {
    __shared__ int s[256];
    int t = threadIdx.x;
    int i = blockIdx.x * 256 + t;
    int v = (i < N_NODES) ? deg[i] : 0;
    s[t] = v;
    __syncthreads();
    for (int off = 1; off < 256; off <<= 1) {
        int u = (t >= off) ? s[t - off] : 0;
        __syncthreads();
        s[t] += u;
        __syncthreads();
    }
    if (i < N_NODES) {
        int excl = s[t] - v + boff[blockIdx.x];
        row_ptr[i] = excl;
        fill[i] = excl;
    }
}

__global__ void k_fill(const int* __restrict__ src, const int* __restrict__ dst,
                       int* __restrict__ fill, int* __restrict__ src_sorted) {
    int e = blockIdx.x * 256 + threadIdx.x;
    if (e < N_EDGES) {
        int p = atomicAdd(&fill[dst[e]], 1);
        src_sorted[p] = src[e];
    }
}

// ---------------- x -> bf16 ----------------
__global__ __launch_bounds__(256) void k_xcvt(const float* __restrict__ x,
                                              unsigned short* __restrict__ xb) {
    int i = blockIdx.x * 256 + threadIdx.x; // one float4 per thread
    float4 v = ((const float4*)x)[i];
    ushort4 o;
    o.x = f2bf(v.x); o.y = f2bf(v.y); o.z = f2bf(v.z); o.w = f2bf(v.w);
    ((ushort4*)xb)[i] = o;
}

// ---------------- mean aggregation: bf16 in / bf16 out, fp32 accumulate ----------------
// one wave per node; lane l owns features 2l, 2l+1 (one uint load per row)
__global__ __launch_bounds__(256) void k_agg(const unsigned short* __restrict__ hb,
                                             const int* __restrict__ row_ptr,
                                             const int* __restrict__ srcs,
                                             unsigned short* __restrict__ meanb) {
    const int w = threadIdx.x >> 6;
    const int l = threadIdx.x & 63;
    const int n = blockIdx.x * 4 + w;
    const int start = row_ptr[n], end = row_ptr[n + 1]; // wave-uniform
    const unsigned int* __restrict__ hp = (const unsigned int*)hb;
    float ax = 0.f, ay = 0.f;
    int e = start;
    for (; e + 4 <= end; e += 4) {
        int s0 = __builtin_amdgcn_readfirstlane(srcs[e]);
        int s1 = __builtin_amdgcn_readfirstlane(srcs[e + 1]);
        int s2 = __builtin_amdgcn_readfirstlane(srcs[e + 2]);
        int s3 = __builtin_amdgcn_readfirstlane(srcs[e + 3]);
        unsigned int u0 = hp[(size_t)s0 * 64 + l];
        unsigned int u1 = hp[(size_t)s1 * 64 + l];
        unsigned int u2 = hp[(size_t)s2 * 64 + l];
        unsigned int u3 = hp[(size_t)s3 * 64 + l];
        ax += (lo_bf(u0) + lo_bf(u1)) + (lo_bf(u2) + lo_bf(u3));
        ay += (hi_bf(u0) + hi_bf(u1)) + (hi_bf(u2) + hi_bf(u3));
    }
    for (; e < end; ++e) {
        int s0 = __builtin_amdgcn_readfirstlane(srcs[e]);
        unsigned int u0 = hp[(size_t)s0 * 64 + l];
        ax += lo_bf(u0); ay += hi_bf(u0);
    }
    int d = end - start;
    float inv = (d > 0) ? 1.f / (float)d : 0.f;
    ushort2 r; r.x = f2bf(ax * inv); r.y = f2bf(ay * inv);
    ((ushort2*)meanb)[(size_t)n * 64 + l] = r;
}

// ---------------- weight convert: Wcat[j] = [wself[j] | wneigh[j]] bf16 ----------------
__global__ void k_wcvt(const float* __restrict__ wself, const float* __restrict__ wneigh,
                       unsigned short* __restrict__ out, int J) {
    int idx = blockIdx.x * 256 + threadIdx.x;
    int j = idx >> 8, k = idx & 255;
    float v = 0.f;
    if (j < J) v = (k < DIM) ? wself[j * DIM + k] : wneigh[j * DIM + (k - DIM)];
    out[idx] = f2bf(v);
}

// ---------------- MFMA GEMM: out[n][j] = cat(Ab,Mb)[n][:] . Wcat[j][:] + b[j] (+relu) ----------------
// One wave per 16-node strip. A frag: lane(m+16*qd) holds A[m][kglob + 0..7] as bf16 v8s
// straight from global. D: col=lane&15, row=qd*4+reg. No LDS, no barriers, no spill.
template <int NTILES, bool RELU, bool OUTBF>
__global__ __launch_bounds__(256) void k_gemm_mfma(const unsigned short* __restrict__ Ab,
                                                   const unsigned short* __restrict__ Mb,
                                                   const unsigned short* __restrict__ Wb,
                                                   const float* __restrict__ bias,
                                                   void* __restrict__ out, int outdim) {
    const int lane = threadIdx.x & 63;
    const int wv = threadIdx.x >> 6;
    const int m0 = (blockIdx.x * 4 + wv) * 16;
    const int m = lane & 15, qd = lane >> 4;
    int node = m0 + m; if (node >= N_NODES) node = N_NODES - 1; // clamp loads
    const unsigned short* __restrict__ arow = Ab + (size_t)node * DIM;
    const unsigned short* __restrict__ mrow = Mb + (size_t)node * DIM;

    v4f acc[NTILES] = {};
    #pragma unroll
    for (int c = 0; c < 8; ++c) {
        const unsigned short* __restrict__ srow = (c < 4) ? arow : mrow;
        v8s af = *(const v8s*)(srow + (c & 3) * 32 + qd * 8);
        const int kglob = c * 32 + qd * 8;
        #pragma unroll
        for (int t = 0; t < NTILES; ++t) {
            v8s wf = *(const v8s*)(Wb + (size_t)(t * 16 + m) * 256 + kglob);
            acc[t] = __builtin_amdgcn_mfma_f32_16x16x32_bf16(af, wf, acc[t], 0, 0, 0);
        }
    }
    #pragma unroll
    for (int t = 0; t < NTILES; ++t) {
        int col = t * 16 + m;
        bool colok = (col < outdim);
        float bv = colok ? bias[col] : 0.f;
        #pragma unroll
        for (int r = 0; r < 4; ++r) {
            int nrow = m0 + qd * 4 + r;
            if (colok && nrow < N_NODES) {
                float v = acc[t][r] + bv;
                if (RELU) v = fmaxf(v, 0.f);
                if (OUTBF) ((unsigned short*)out)[(size_t)nrow * outdim + col] = f2bf(v);
                else       ((float*)out)[(size_t)nrow * outdim + col] = v;
            }
        }
    }
}

extern "C" void kernel_launch(void* const* d_in, const int* in_sizes, int n_in,
                              void* d_out, int out_size, void* d_ws, size_t ws_size,
                              hipStream_t stream) {
    const float* x   = (const float*)d_in[0];
    const int*   src = (const int*)d_in[1];
    const int*   dst = (const int*)d_in[2];
    const float* ws1 = (const float*)d_in[3];
    const float* wn1 = (const float*)d_in[4];
    const float* b1  = (const float*)d_in[5];
    const float* ws2 = (const float*)d_in[6];
    const float* wn2 = (const float*)d_in[7];
    const float* b2  = (const float*)d_in[8];
    const float* ws3 = (const float*)d_in[9];
    const float* wn3 = (const float*)d_in[10];
    const float* b3  = (const float*)d_in[11];

    char* p = (char*)d_ws;
    auto alloc = [&](size_t bytes) { char* r = p; p += (bytes + 255) & ~(size_t)255; return r; };
    int*   deg     = (int*)alloc((size_t)N_NODES * 4);
    int*   row_ptr = (int*)alloc((size_t)(N_NODES + 1) * 4);
    int*   fill    = (int*)alloc((size_t)N_NODES * 4);
    int*   srcs    = (int*)alloc((size_t)N_EDGES * 4);
    int*   bsum    = (int*)alloc((size_t)NB_SCAN * 4);
    int*   boff    = (int*)alloc((size_t)NB_SCAN * 4);
    unsigned short* xb    = (unsigned short*)alloc((size_t)N_NODES * DIM * 2);
    unsigned short* meanb = (unsigned short*)alloc((size_t)N_NODES * DIM * 2);
    unsigned short* h1b   = (unsigned short*)alloc((size_t)N_NODES * DIM * 2);
    unsigned short* h2b   = (unsigned short*)alloc((size_t)N_NODES * DIM * 2);
    unsigned short* wb1 = (unsigned short*)alloc((size_t)DIM * 256 * 2);
    unsigned short* wb2 = (unsigned short*)alloc((size_t)DIM * 256 * 2);
    unsigned short* wb3 = (unsigned short*)alloc((size_t)48 * 256 * 2);

    // conversions (tiny / 38 MB total)
    k_xcvt<<<(N_NODES * DIM / 4 + 255) / 256, 256, 0, stream>>>(x, xb);
    k_wcvt<<<DIM, 256, 0, stream>>>(ws1, wn1, wb1, DIM);
    k_wcvt<<<DIM, 256, 0, stream>>>(ws2, wn2, wb2, DIM);
    k_wcvt<<<48,  256, 0, stream>>>(ws3, wn3, wb3, OUTD);

    // CSR build (ws re-poisoned every call -> rebuild every call)
    hipMemsetAsync(deg, 0, (size_t)N_NODES * 4, stream);
    k_count<<<(N_EDGES + 255) / 256, 256, 0, stream>>>(dst, deg);
    k_bsum<<<NB_SCAN, 256, 0, stream>>>(deg, bsum);
    k_scanb<<<1, 256, 0, stream>>>(bsum, boff, row_ptr);
    k_scatter<<<NB_SCAN, 256, 0, stream>>>(deg, boff, row_ptr, fill);
    k_fill<<<(N_EDGES + 255) / 256, 256, 0, stream>>>(src, dst, fill, srcs);

    const int GB = (N_NODES + 63) / 64; // 782 blocks, 4 waves x 16 nodes

    // layer 1
    k_agg<<<N_NODES / 4, 256, 0, stream>>>(xb, row_ptr, srcs, meanb);
    k_gemm_mfma<8, true, true><<<GB, 256, 0, stream>>>(xb, meanb, wb1, b1, h1b, DIM);
    // layer 2
    k_agg<<<N_NODES / 4, 256, 0, stream>>>(h1b, row_ptr, srcs, meanb);
    k_gemm_mfma<8, true, true><<<GB, 256, 0, stream>>>(h1b, meanb, wb2, b2, h2b, DIM);
    // layer 3
    k_agg<<<N_NODES / 4, 256, 0, stream>>>(h2b, row_ptr, srcs, meanb);
    k_gemm_mfma<3, false, false><<<GB, 256, 0, stream>>>(h2b, meanb, wb3, b3, d_out, OUTD);
}